// Round 13
// baseline (95.006 us; speedup 1.0000x reference)
//
#include <hip/hip_runtime.h>
#include <stdint.h>

// ---------------------------------------------------------------------------
// NAT block forward: B=2, H=W=56, C=128, nh=4, hd=32, K=7, depth=2, hidden=512
// Round 13: mlp_fused3 — per-lane direct-from-L2 weight B-fragments
// (no sW staging, 8 barriers instead of 22, LDS 29 KB). 8 launches.
// ---------------------------------------------------------------------------

typedef __attribute__((ext_vector_type(8))) short bf16x8;
typedef __attribute__((ext_vector_type(4))) float f32x4;

__device__ __forceinline__ float bf2f(uint16_t u) {
  union { uint32_t u; float f; } t;
  t.u = (uint32_t)u << 16;
  return t.f;
}
__device__ __forceinline__ uint16_t f2bf(float f) {
  union { float f; uint32_t u; } t;
  t.f = f;
  return (uint16_t)((t.u + 0x7FFFu + ((t.u >> 16) & 1u)) >> 16);
}

// ---------------------------------------------------------------------------
// One-shot weight prep: 9 transpose+bf16 jobs in one launch (672 blocks).
// ---------------------------------------------------------------------------
struct PrepArgs {
  const float* src[9];
  uint16_t* dst[9];
  int K[9], N[9];
  int cum[10];
};

__global__ __launch_bounds__(256) void prep_weights(PrepArgs a) {
  __shared__ float t[32][33];
  int bt = blockIdx.x;
  int j = 0;
#pragma unroll
  for (int u = 0; u < 9; ++u)
    if (bt >= a.cum[u + 1]) j = u + 1;
  int lt = bt - a.cum[j];
  const float* w = a.src[j];
  uint16_t* wt = a.dst[j];
  int K = a.K[j], N = a.N[j];
  int tn = N >> 5;
  int n0 = (lt % tn) * 32, k0 = (lt / tn) * 32;
  int tx = threadIdx.x & 31, ty = threadIdx.x >> 5;
#pragma unroll
  for (int r2 = 0; r2 < 32; r2 += 8)
    t[ty + r2][tx] = w[(size_t)(k0 + ty + r2) * N + n0 + tx];
  __syncthreads();
#pragma unroll
  for (int r2 = 0; r2 < 32; r2 += 8)
    wt[(size_t)(n0 + ty + r2) * K + k0 + tx] = f2bf(t[tx][ty + r2]);
}

// LayerNorm over C=256 of (p0+p1+p2), fp32 -> fp32. Wave per pixel, float4.
__global__ __launch_bounds__(256) void ln256_kernel(const float* __restrict__ p0,
                                                    const float* __restrict__ p1,
                                                    const float* __restrict__ p2,
                                                    float* __restrict__ out,
                                                    const float* __restrict__ w,
                                                    const float* __restrict__ b) {
  int wave = threadIdx.x >> 6, lane = threadIdx.x & 63;
  int pix = blockIdx.x * 4 + wave;
  size_t base = (size_t)pix * 256 + lane * 4;
  float4 a0 = *(const float4*)(p0 + base);
  float4 a1 = *(const float4*)(p1 + base);
  float4 a2 = *(const float4*)(p2 + base);
  float4 v;
  v.x = a0.x + a1.x + a2.x;
  v.y = a0.y + a1.y + a2.y;
  v.z = a0.z + a1.z + a2.z;
  v.w = a0.w + a1.w + a2.w;
  float s = v.x + v.y + v.z + v.w;
  float s2 = v.x * v.x + v.y * v.y + v.z * v.z + v.w * v.w;
#pragma unroll
  for (int off = 32; off; off >>= 1) {
    s += __shfl_xor(s, off, 64);
    s2 += __shfl_xor(s2, off, 64);
  }
  float mu = s * (1.f / 256.f);
  float var = s2 * (1.f / 256.f) - mu * mu;
  float r = rsqrtf(var + 1e-5f);
  float4 wv = *(const float4*)(w + lane * 4);
  float4 bv = *(const float4*)(b + lane * 4);
  float4 o;
  o.x = (v.x - mu) * r * wv.x + bv.x;
  o.y = (v.y - mu) * r * wv.y + bv.y;
  o.z = (v.z - mu) * r * wv.z + bv.z;
  o.w = (v.w - mu) * r * wv.w + bv.w;
  *(float4*)(out + base) = o;
}

// ---------------------------------------------------------------------------
// MFMA GEMM, 32x64 tile, 4 waves (2x2), wave = 16x32. Used for qkv0 (LNF=1).
// ---------------------------------------------------------------------------
template <int KD, int ND, int ACT, int RES, int OUTB, int LNF>
__global__ __launch_bounds__(256) void mfma_gemm32(
    const uint16_t* __restrict__ A, const float* __restrict__ Af,
    const float* __restrict__ lnw, const float* __restrict__ lnb,
    const uint16_t* __restrict__ Wt, const float* __restrict__ bias,
    const float* __restrict__ res, float* __restrict__ outf,
    uint16_t* __restrict__ outb, float* __restrict__ outf2, int M) {
  __shared__ __align__(16) char smem[26112];  // sA[32][136] | sB[64][136]
  uint16_t(*sA)[136] = (uint16_t(*)[136])smem;
  uint16_t(*sB)[136] = (uint16_t(*)[136])(smem + 8704);
  float(*sC)[68] = (float(*)[68])smem;

  int m0 = blockIdx.x * 32, n0 = blockIdx.y * 64;
  int tid = threadIdx.x, lane = tid & 63, wid = tid >> 6;
  int wr = (wid >> 1) * 16, wc = (wid & 1) * 32;
  int lc = lane & 15, g = lane >> 4;
  int lko = g * 8;

  f32x4 acc0 = {0.f, 0.f, 0.f, 0.f}, acc1 = acc0;

  constexpr int NCH = KD / 128;
#pragma unroll
  for (int c = 0; c < NCH; ++c) {
    if constexpr (LNF) {
      int r = tid >> 3, qt = tid & 7;
      const float4* xr = (const float4*)(Af + (size_t)(m0 + r) * 128 + qt * 16);
      float4 xv[4];
      float s = 0.f, s2 = 0.f;
#pragma unroll
      for (int u = 0; u < 4; ++u) {
        xv[u] = xr[u];
        s += xv[u].x + xv[u].y + xv[u].z + xv[u].w;
        s2 += xv[u].x * xv[u].x + xv[u].y * xv[u].y + xv[u].z * xv[u].z + xv[u].w * xv[u].w;
      }
      s += __shfl_xor(s, 1, 64);
      s += __shfl_xor(s, 2, 64);
      s += __shfl_xor(s, 4, 64);
      s2 += __shfl_xor(s2, 1, 64);
      s2 += __shfl_xor(s2, 2, 64);
      s2 += __shfl_xor(s2, 4, 64);
      float mu = s * (1.f / 128.f);
      float var = s2 * (1.f / 128.f) - mu * mu;
      float rstd = rsqrtf(var + 1e-5f);
      const float* lw = lnw + qt * 16;
      const float* lb = lnb + qt * 16;
      union { uint16_t us[8]; bf16x8 v; } tq[2];
#pragma unroll
      for (int u = 0; u < 4; ++u) {
        tq[u >> 1].us[(u & 1) * 4 + 0] = f2bf((xv[u].x - mu) * rstd * lw[u * 4 + 0] + lb[u * 4 + 0]);
        tq[u >> 1].us[(u & 1) * 4 + 1] = f2bf((xv[u].y - mu) * rstd * lw[u * 4 + 1] + lb[u * 4 + 1]);
        tq[u >> 1].us[(u & 1) * 4 + 2] = f2bf((xv[u].z - mu) * rstd * lw[u * 4 + 2] + lb[u * 4 + 2]);
        tq[u >> 1].us[(u & 1) * 4 + 3] = f2bf((xv[u].w - mu) * rstd * lw[u * 4 + 3] + lb[u * 4 + 3]);
      }
      *(bf16x8*)&sA[r][qt * 16] = tq[0].v;
      *(bf16x8*)&sA[r][qt * 16 + 8] = tq[1].v;
    } else {
#pragma unroll
      for (int it = 0; it < 2; ++it) {
        int chunk = tid + it * 256;
        int row = chunk >> 4, kc = (chunk & 15) * 8;
        *(bf16x8*)&sA[row][kc] =
            *(const bf16x8*)(A + (size_t)(m0 + row) * KD + c * 128 + kc);
      }
    }
#pragma unroll
    for (int it = 0; it < 4; ++it) {
      int chunk = tid + it * 256;
      int row = chunk >> 4, kc = (chunk & 15) * 8;
      *(bf16x8*)&sB[row][kc] =
          *(const bf16x8*)(Wt + (size_t)(n0 + row) * KD + c * 128 + kc);
    }
    __syncthreads();
#pragma unroll
    for (int kk = 0; kk < 128; kk += 32) {
      bf16x8 a0 = *(const bf16x8*)&sA[wr + lc][kk + lko];
      bf16x8 b0 = *(const bf16x8*)&sB[wc + lc][kk + lko];
      bf16x8 b1 = *(const bf16x8*)&sB[wc + 16 + lc][kk + lko];
      acc0 = __builtin_amdgcn_mfma_f32_16x16x32_bf16(a0, b0, acc0, 0, 0, 0);
      acc1 = __builtin_amdgcn_mfma_f32_16x16x32_bf16(a0, b1, acc1, 0, 0, 0);
    }
    __syncthreads();
  }

  {
    float bv0 = bias ? bias[n0 + wc + lc] : 0.f;
    float bv1 = bias ? bias[n0 + wc + lc + 16] : 0.f;
#pragma unroll
    for (int ni = 0; ni < 2; ++ni) {
      float bv = ni ? bv1 : bv0;
      f32x4 av = ni ? acc1 : acc0;
#pragma unroll
      for (int j = 0; j < 4; ++j) {
        float a = av[j] + bv;
        if (ACT) a = 0.5f * a * (1.f + erff(a * 0.70710678118654752f));
        sC[wr + g * 4 + j][wc + ni * 16 + lc] = a;
      }
    }
    __syncthreads();
    int r = tid >> 3, cs = (tid & 7) * 8;
    int grow = m0 + r;
    if (grow < M) {
      const float4* cp = (const float4*)&sC[r][cs];
      float4 c4[2] = {cp[0], cp[1]};
      if (RES) {
        const float4* rp = (const float4*)(res + (size_t)grow * ND + n0 + cs);
#pragma unroll
        for (int u = 0; u < 2; ++u) {
          float4 rv = rp[u];
          c4[u].x += rv.x; c4[u].y += rv.y; c4[u].z += rv.z; c4[u].w += rv.w;
        }
      }
      if (OUTB) {
        union { uint16_t us[8]; bf16x8 v; } t;
#pragma unroll
        for (int u = 0; u < 2; ++u) {
          t.us[u * 4 + 0] = f2bf(c4[u].x);
          t.us[u * 4 + 1] = f2bf(c4[u].y);
          t.us[u * 4 + 2] = f2bf(c4[u].z);
          t.us[u * 4 + 3] = f2bf(c4[u].w);
        }
        *(bf16x8*)(outb + (size_t)grow * ND + n0 + cs) = t.v;
      } else {
        float4* op = (float4*)(outf + (size_t)grow * ND + n0 + cs);
        op[0] = c4[0];
        op[1] = c4[1];
        if (outf2) {
          float4* op2 = (float4*)(outf2 + (size_t)grow * ND + n0 + cs);
          op2[0] = c4[0];
          op2[1] = c4[1];
        }
      }
    }
  }
}

// ---------------------------------------------------------------------------
// Fused MLP tail v3 (+ optional next-layer LN1+qkv): 392 blocks x 512 threads,
// 16 rows/block. Weights read as per-lane direct B-fragments from L2
// (no LDS weight staging, 8 barriers). LDS 29 KB.
//   y  = x + proj(att) + pb
//   x' = y + fc2(gelu(fc1(LN2(y)))) + f2b          -> xout (+out2)
//   if WQKV: qkv = LN1'(x') @ qkvw' + qkvb'        -> qkvout
// ---------------------------------------------------------------------------
template <int WQKV>
__global__ __launch_bounds__(512) void mlp_fused3(
    const uint16_t* __restrict__ att,   // [6272][128] bf16
    const float* __restrict__ xin,      // [6272][128] f32 (proj residual)
    const uint16_t* __restrict__ pwt,   // [128][128]
    const float* __restrict__ pb,
    const float* __restrict__ n2w, const float* __restrict__ n2b,
    const uint16_t* __restrict__ f1wt,  // [512][128]
    const float* __restrict__ f1b,
    const uint16_t* __restrict__ f2wt,  // [128][512]
    const float* __restrict__ f2b,
    float* __restrict__ xout,
    float* __restrict__ out2,
    const float* __restrict__ n1w, const float* __restrict__ n1b,
    const uint16_t* __restrict__ qwt,   // next-layer qkv [384][128]
    const float* __restrict__ qb,
    uint16_t* __restrict__ qkvout) {
  __shared__ __align__(16) uint16_t sA[16][136];   // 4352 B (activations bf16)
  __shared__ __align__(16) float sY[16][132];      // 8448 B (y, f32)
  __shared__ __align__(16) char sHraw[16640];      // sH bf16[16][520] | sC f32[16][132]
  uint16_t(*sH)[520] = (uint16_t(*)[520])sHraw;
  float(*sC)[132] = (float(*)[132])sHraw;

  const f32x4 fz = {0.f, 0.f, 0.f, 0.f};
  int m0 = blockIdx.x * 16;
  int tid = threadIdx.x;
  int lane = tid & 63, wid = tid >> 6;  // 8 waves
  int lc = lane & 15, g = lane >> 4;
  int rr = tid >> 5, cc = tid & 31;     // 16 rows x 32 threads (4 cols each)

  float4 rx = *(const float4*)(xin + (size_t)(m0 + rr) * 128 + cc * 4);

  if (tid < 256) {
    int r = tid >> 4, q = tid & 15;
    *(bf16x8*)&sA[r][q * 8] = *(const bf16x8*)(att + (size_t)(m0 + r) * 128 + q * 8);
  }
  __syncthreads();  // B1: sA(att) ready

  // --- proj: wave w -> cols w*16..+15, B direct from global ---
  {
    f32x4 acc = fz;
#pragma unroll
    for (int ks = 0; ks < 4; ++ks) {
      bf16x8 a = *(const bf16x8*)&sA[lc][ks * 32 + g * 8];
      bf16x8 b = *(const bf16x8*)(pwt + (size_t)(wid * 16 + lc) * 128 + ks * 32 + g * 8);
      acc = __builtin_amdgcn_mfma_f32_16x16x32_bf16(a, b, acc, 0, 0, 0);
    }
    float bv = pb[wid * 16 + lc];
#pragma unroll
    for (int j = 0; j < 4; ++j) sY[g * 4 + j][wid * 16 + lc] = acc[j] + bv;
  }
  __syncthreads();  // B2: sY(proj) ready

  // --- y = proj + x; LN2; norm -> sA ---
  {
    float4 sv = *(const float4*)&sY[rr][cc * 4];
    float4 y;
    y.x = sv.x + rx.x; y.y = sv.y + rx.y; y.z = sv.z + rx.z; y.w = sv.w + rx.w;
    float s = y.x + y.y + y.z + y.w;
    float s2 = y.x * y.x + y.y * y.y + y.z * y.z + y.w * y.w;
#pragma unroll
    for (int off = 1; off < 32; off <<= 1) {
      s += __shfl_xor(s, off, 64);
      s2 += __shfl_xor(s2, off, 64);
    }
    float mu = s * (1.f / 128.f);
    float var = s2 * (1.f / 128.f) - mu * mu;
    float rstd = rsqrtf(var + 1e-5f);
    *(float4*)&sY[rr][cc * 4] = y;
    float4 lw = *(const float4*)(n2w + cc * 4);
    float4 lb = *(const float4*)(n2b + cc * 4);
    ushort4 nv;
    nv.x = f2bf((y.x - mu) * rstd * lw.x + lb.x);
    nv.y = f2bf((y.y - mu) * rstd * lw.y + lb.y);
    nv.z = f2bf((y.z - mu) * rstd * lw.z + lb.z);
    nv.w = f2bf((y.w - mu) * rstd * lw.w + lb.w);
    *(ushort4*)&sA[rr][cc * 4] = nv;
  }
  __syncthreads();  // B3: sA(norm), sY(y) ready

  // --- fc1 + GELU: wave w -> cols {ch*128 + w*16}, 16 MFMA, no chunk barriers ---
#pragma unroll
  for (int ch = 0; ch < 4; ++ch) {
    f32x4 acc = fz;
#pragma unroll
    for (int ks = 0; ks < 4; ++ks) {
      bf16x8 a = *(const bf16x8*)&sA[lc][ks * 32 + g * 8];
      bf16x8 b = *(const bf16x8*)(f1wt + (size_t)(ch * 128 + wid * 16 + lc) * 128 +
                                  ks * 32 + g * 8);
      acc = __builtin_amdgcn_mfma_f32_16x16x32_bf16(a, b, acc, 0, 0, 0);
    }
    int col = ch * 128 + wid * 16 + lc;
    float bv = f1b[col];
#pragma unroll
    for (int j = 0; j < 4; ++j) {
      float h = acc[j] + bv;
      h = 0.5f * h * (1.f + erff(h * 0.70710678118654752f));
      sH[g * 4 + j][col] = f2bf(h);
    }
  }
  __syncthreads();  // B4: sH ready

  // --- fc2: K=512, 16 k-steps, B direct ---
  f32x4 acc2 = fz;
#pragma unroll
  for (int ks = 0; ks < 16; ++ks) {
    bf16x8 a = *(const bf16x8*)&sH[lc][ks * 32 + g * 8];
    bf16x8 b = *(const bf16x8*)(f2wt + (size_t)(wid * 16 + lc) * 512 + ks * 32 + g * 8);
    acc2 = __builtin_amdgcn_mfma_f32_16x16x32_bf16(a, b, acc2, 0, 0, 0);
  }
  __syncthreads();  // B5: sH reads done (sC aliases sH)

  {
    int col = wid * 16 + lc;
    float bv = f2b[col];
#pragma unroll
    for (int j = 0; j < 4; ++j) sC[g * 4 + j][col] = acc2[j] + bv;
  }
  __syncthreads();  // B6: sC ready

  // --- x' = y + mlp_out; store; (WQKV) LN1 -> sA ---
  {
    float4 cv = *(const float4*)&sC[rr][cc * 4];
    float4 yv = *(const float4*)&sY[rr][cc * 4];
    float4 o;
    o.x = cv.x + yv.x; o.y = cv.y + yv.y; o.z = cv.z + yv.z; o.w = cv.w + yv.w;
    *(float4*)(xout + (size_t)(m0 + rr) * 128 + cc * 4) = o;
    if (out2) *(float4*)(out2 + (size_t)(m0 + rr) * 128 + cc * 4) = o;
    if constexpr (WQKV) {
      float s = o.x + o.y + o.z + o.w;
      float s2 = o.x * o.x + o.y * o.y + o.z * o.z + o.w * o.w;
#pragma unroll
      for (int off = 1; off < 32; off <<= 1) {
        s += __shfl_xor(s, off, 64);
        s2 += __shfl_xor(s2, off, 64);
      }
      float mu = s * (1.f / 128.f);
      float var = s2 * (1.f / 128.f) - mu * mu;
      float rstd = rsqrtf(var + 1e-5f);
      float4 lw = *(const float4*)(n1w + cc * 4);
      float4 lb = *(const float4*)(n1b + cc * 4);
      ushort4 nv;
      nv.x = f2bf((o.x - mu) * rstd * lw.x + lb.x);
      nv.y = f2bf((o.y - mu) * rstd * lw.y + lb.y);
      nv.z = f2bf((o.z - mu) * rstd * lw.z + lb.z);
      nv.w = f2bf((o.w - mu) * rstd * lw.w + lb.w);
      *(ushort4*)&sA[rr][cc * 4] = nv;
    }
  }

  if constexpr (WQKV) {
    __syncthreads();  // B7: sA(LN1) ready; sC reads done (sH aliases sC)
    // --- qkv: wave w -> cols {ch*128 + w*16}, 12 MFMA, outputs via sH ---
#pragma unroll
    for (int ch = 0; ch < 3; ++ch) {
      f32x4 acc = fz;
#pragma unroll
      for (int ks = 0; ks < 4; ++ks) {
        bf16x8 a = *(const bf16x8*)&sA[lc][ks * 32 + g * 8];
        bf16x8 b = *(const bf16x8*)(qwt + (size_t)(ch * 128 + wid * 16 + lc) * 128 +
                                    ks * 32 + g * 8);
        acc = __builtin_amdgcn_mfma_f32_16x16x32_bf16(a, b, acc, 0, 0, 0);
      }
      int col = ch * 128 + wid * 16 + lc;
      float bv = qb[col];
#pragma unroll
      for (int j = 0; j < 4; ++j) sH[g * 4 + j][col] = f2bf(acc[j] + bv);
    }
    __syncthreads();  // B8: sH(qkv) ready
    for (int idx = tid; idx < 1536; idx += 512) {
      int row = idx / 96, colc = (idx % 96) * 4;
      *(ushort4*)(qkvout + (size_t)(m0 + row) * 384 + colc) =
          *(const ushort4*)&sH[row][colc];
    }
  }
}

// ---------------------------------------------------------------------------
// Neighborhood attention via MFMA. Block = (b, head, 8x4 q-tile), 784 blocks
// of 128 threads (2 waves x 16 q). Halo 10x14 = 140 keys, padded to 160.
// ---------------------------------------------------------------------------
#define KSWZ(row, colbytes) (((row) * 64 + (colbytes)) ^ (((row) & 7) << 4))

__global__ __launch_bounds__(128) void natten_mfma(const uint16_t* __restrict__ qkv,
                                                   const float* __restrict__ rpb,
                                                   uint16_t* __restrict__ out) {
  __shared__ uint16_t s_k[144 * 32];
  __shared__ uint16_t s_vt[32][168];
  __shared__ uint16_t s_p[32][168];
  __shared__ float s_rpb[169];

  int tid = threadIdx.x;
  int blk = blockIdx.x;
  int bh = blk & 7, tile = blk >> 3;
  int b = bh >> 2, head = bh & 3;
  int ti = tile / 7, tj = tile % 7;
  int i0 = ti * 4, j0 = tj * 8;
  int rbase = min(max(i0 - 3, 0), 46);
  int cbase = min(max(j0 - 3, 0), 42);

  const bf16x8 bz = {0, 0, 0, 0, 0, 0, 0, 0};
  const f32x4 fz = {0.f, 0.f, 0.f, 0.f};

  if (tid < 16)
    *(bf16x8*)((char*)s_k + KSWZ(140 + (tid >> 2), (tid & 3) * 16)) = bz;
  for (int idx = tid; idx < 640; idx += 128) s_vt[idx & 31][140 + (idx >> 5)] = 0;
  for (int idx = tid; idx < 512; idx += 128) s_p[idx & 31][144 + (idx >> 5)] = 0;
  for (int idx = tid; idx < 560; idx += 128) {
    int pos = idx >> 2, ch = (idx & 3) * 8;
    int r = rbase + pos / 14, c = cbase + pos % 14;
    const uint16_t* base = qkv + ((size_t)(b * 3136 + r * 56 + c)) * 384 + head * 32 + ch;
    bf16x8 kv = *(const bf16x8*)(base + 128);
    bf16x8 vv = *(const bf16x8*)(base + 256);
    *(bf16x8*)((char*)s_k + KSWZ(pos, ch * 2)) = kv;
#pragma unroll
    for (int e = 0; e < 8; ++e) s_vt[ch + e][pos] = (uint16_t)vv[e];
  }
  for (int idx = tid; idx < 169; idx += 128) s_rpb[idx] = rpb[head * 169 + idx];
  __syncthreads();

  int lane = tid & 63, wq = tid >> 6;
  int lc = lane & 15, g = lane >> 4;
  int q0 = wq * 16;

  int pA = q0 + lc;
  int piA = i0 + (pA >> 3), pjA = j0 + (pA & 7);
  bf16x8 qfrag =
      *(const bf16x8*)(qkv + ((size_t)(b * 3136 + piA * 56 + pjA)) * 384 + head * 32 + g * 8);

  f32x4 S[9];
#pragma unroll
  for (int t = 0; t < 9; ++t) {
    bf16x8 kfrag = *(const bf16x8*)((char*)s_k + KSWZ(t * 16 + lc, g * 16));
    S[t] = __builtin_amdgcn_mfma_f32_16x16x32_bf16(qfrag, kfrag, fz, 0, 0, 0);
  }

  int qi = wq * 2 + (g >> 1);
  int i = i0 + qi;
  int a = min(max(i - 3, 0), 49) - rbase;
  int brc = 6 - (i0 - rbase) - qi;
  int bj[4], bcc[4];
#pragma unroll
  for (int jj = 0; jj < 4; ++jj) {
    int qj = 4 * (g & 1) + jj;
    int j = j0 + qj;
    bj[jj] = min(max(j - 3, 0), 49) - cbase;
    bcc[jj] = 6 - (j0 - cbase) - qj;
  }

  float mx[4] = {-1e30f, -1e30f, -1e30f, -1e30f};
  int kr = (lc >= 14) ? 1 : 0;
  int kc = lc - 14 * kr;
#pragma unroll
  for (int t = 0; t < 9; ++t) {
    bool vr = (kr >= a) && (kr <= a + 6);
    int brrow = (kr + brc) * 13;
#pragma unroll
    for (int jj = 0; jj < 4; ++jj) {
      float sv = S[t][jj] * 0.17677669529663687f;
      bool v = vr && (kc >= bj[jj]) && (kc <= bj[jj] + 6);
      int bidx = v ? (brrow + kc + bcc[jj]) : 0;
      float val = v ? (sv + s_rpb[bidx]) : -1e30f;
      S[t][jj] = val;
      mx[jj] = fmaxf(mx[jj], val);
    }
    kr += 1;
    kc += 2;
    if (kc >= 14) { kc -= 14; kr += 1; }
  }
#pragma unroll
  for (int jj = 0; jj < 4; ++jj) {
#pragma unroll
    for (int off = 1; off < 16; off <<= 1) mx[jj] = fmaxf(mx[jj], __shfl_xor(mx[jj], off, 64));
  }

  float sm[4] = {0.f, 0.f, 0.f, 0.f};
#pragma unroll
  for (int t = 0; t < 9; ++t) {
#pragma unroll
    for (int jj = 0; jj < 4; ++jj) {
      float e = __expf(S[t][jj] - mx[jj]);
      sm[jj] += e;
      s_p[q0 + g * 4 + jj][t * 16 + lc] = f2bf(e);
    }
  }
#pragma unroll
  for (int jj = 0; jj < 4; ++jj) {
#pragma unroll
    for (int off = 1; off < 16; off <<= 1) sm[jj] += __shfl_xor(sm[jj], off, 64);
    sm[jj] = 1.f / sm[jj];
  }

  __syncthreads();

  f32x4 O[2] = {fz, fz};
#pragma unroll
  for (int ks = 0; ks < 5; ++ks) {
    bf16x8 pa = *(const bf16x8*)&s_p[q0 + lc][ks * 32 + g * 8];
#pragma unroll
    for (int dt = 0; dt < 2; ++dt) {
      bf16x8 vb = *(const bf16x8*)&s_vt[dt * 16 + lc][ks * 32 + g * 8];
      O[dt] = __builtin_amdgcn_mfma_f32_16x16x32_bf16(pa, vb, O[dt], 0, 0, 0);
    }
  }

#pragma unroll
  for (int jj = 0; jj < 4; ++jj) {
    int q = q0 + g * 4 + jj;
    int pi = i0 + (q >> 3), pj = j0 + (q & 7);
    size_t ob = ((size_t)(b * 3136 + pi * 56 + pj)) * 128 + head * 32;
    out[ob + lc] = f2bf(O[0][jj] * sm[jj]);
    out[ob + 16 + lc] = f2bf(O[1][jj] * sm[jj]);
  }
}

// ---------------------------------------------------------------------------
// Conv GEMM, split-K by kh (blockIdx.z). Grid (49, 4, 3). 32x64 tile.
// ---------------------------------------------------------------------------
__global__ __launch_bounds__(256) void conv_gemm32(const float* __restrict__ x,
                                                   const uint16_t* __restrict__ Wt,
                                                   float* __restrict__ parts) {
  __shared__ __align__(16) char smem[26112];
  uint16_t(*sA)[136] = (uint16_t(*)[136])smem;
  uint16_t(*sB)[136] = (uint16_t(*)[136])(smem + 8704);
  float(*sC)[68] = (float(*)[68])smem;

  int m0 = blockIdx.x * 32, n0 = blockIdx.y * 64, kh = blockIdx.z;
  float* part = parts + (size_t)kh * 1568 * 256;
  int tid = threadIdx.x, lane = tid & 63, wid = tid >> 6;
  int wr = (wid >> 1) * 16, wc = (wid & 1) * 32;
  int lc = lane & 15, g = lane >> 4;
  int lko = g * 8;

  f32x4 acc0 = {0.f, 0.f, 0.f, 0.f}, acc1 = acc0;

  int r = tid >> 3, qt = tid & 7;
  int opix = m0 + r;
  int ow = opix % 28, oh = (opix / 28) % 28, bb = opix / 784;
  int ih = 2 * oh - 1 + kh;
  bool rowok = (ih >= 0) && (ih < 56);

#pragma unroll
  for (int kwc = 0; kwc < 3; ++kwc) {
    int iw = 2 * ow - 1 + kwc;
    float4 xv[4] = {{0.f, 0.f, 0.f, 0.f}, {0.f, 0.f, 0.f, 0.f},
                    {0.f, 0.f, 0.f, 0.f}, {0.f, 0.f, 0.f, 0.f}};
    if (rowok && iw >= 0 && iw < 56) {
      const float4* p =
          (const float4*)(x + (size_t)((bb * 56 + ih) * 56 + iw) * 128 + qt * 16);
#pragma unroll
      for (int u = 0; u < 4; ++u) xv[u] = p[u];
    }
    union { uint16_t us[8]; bf16x8 v; } tq[2];
#pragma unroll
    for (int u = 0; u < 4; ++u) {
      tq[u >> 1].us[(u & 1) * 4 + 0] = f2bf(xv[u].x);
      tq[u >> 1].us[(u & 1) * 4 + 1] = f2bf(xv[u].y);
      tq[u >> 1].us[(u & 1) * 4 + 2] = f2bf(xv[u].z);
      tq[u >> 1].us[(u & 1) * 4 + 3] = f2bf(xv[u].w);
    }
    *(bf16x8*)&sA[r][qt * 16] = tq[0].v;
    *(bf16x8*)&sA[r][qt * 16 + 8] = tq[1].v;
#pragma unroll
    for (int it = 0; it < 4; ++it) {
      int chunk = tid + it * 256;
      int row = chunk >> 4, kc = (chunk & 15) * 8;
      *(bf16x8*)&sB[row][kc] =
          *(const bf16x8*)(Wt + (size_t)(n0 + row) * 1152 + kh * 384 + kwc * 128 + kc);
    }
    __syncthreads();
#pragma unroll
    for (int kk = 0; kk < 128; kk += 32) {
      bf16x8 a0 = *(const bf16x8*)&sA[wr + lc][kk + lko];
      bf16x8 b0 = *(const bf16x8*)&sB[wc + lc][kk + lko];
      bf16x8 b1 = *(const bf16x8*)&sB[wc + 16 + lc][kk + lko];
      acc0 = __builtin_amdgcn_mfma_f32_16x16x32_bf16(a0, b0, acc0, 0, 0, 0);
      acc1 = __builtin_amdgcn_mfma_f32_16x16x32_bf16(a0, b1, acc1, 0, 0, 0);
    }
    __syncthreads();
  }

#pragma unroll
  for (int ni = 0; ni < 2; ++ni) {
    f32x4 av = ni ? acc1 : acc0;
#pragma unroll
    for (int j = 0; j < 4; ++j) sC[wr + g * 4 + j][wc + ni * 16 + lc] = av[j];
  }
  __syncthreads();
  int rr = tid >> 3, cs = (tid & 7) * 8;
  int grow = m0 + rr;
  if (grow < 1568) {
    const float4* cp = (const float4*)&sC[rr][cs];
    float4* op = (float4*)(part + (size_t)grow * 256 + n0 + cs);
    op[0] = cp[0];
    op[1] = cp[1];
  }
}

extern "C" void kernel_launch(void* const* d_in, const int* in_sizes, int n_in,
                              void* d_out, int out_size, void* d_ws, size_t ws_size,
                              hipStream_t stream) {
  const float* x    = (const float*)d_in[0];
  const float* n1w  = (const float*)d_in[1];
  const float* n1b  = (const float*)d_in[2];
  const float* qkvw = (const float*)d_in[3];
  const float* qkvb = (const float*)d_in[4];
  const float* rpb  = (const float*)d_in[5];
  const float* pw   = (const float*)d_in[6];
  const float* pb   = (const float*)d_in[7];
  const float* n2w  = (const float*)d_in[8];
  const float* n2b  = (const float*)d_in[9];
  const float* f1w  = (const float*)d_in[10];
  const float* f1b  = (const float*)d_in[11];
  const float* f2w  = (const float*)d_in[12];
  const float* f2b  = (const float*)d_in[13];
  const float* cw   = (const float*)d_in[14];
  const float* dnw  = (const float*)d_in[15];
  const float* dnb  = (const float*)d_in[16];
  float* out = (float*)d_out;

  char* wsb = (char*)d_ws;
  float*    xbuf    = (float*)(wsb + 0);           // 3211264 B
  uint16_t* qkv_b   = (uint16_t*)(wsb + 3211264);  // 4816896 B
  uint16_t* att_b   = (uint16_t*)(wsb + 8028160);  // 1605632 B
  float*    parts   = (float*)(wsb + 16056320);    // 3 x 1605632 B
  uint16_t* wts     = (uint16_t*)(wsb + 20873216); // 1376256 B
  uint16_t* qkvwt = wts;            // 2 x 384x128
  uint16_t* pwt   = wts + 98304;    // 2 x 128x128
  uint16_t* f1wt  = wts + 131072;   // 2 x 512x128
  uint16_t* f2wt  = wts + 262144;   // 2 x 128x512
  uint16_t* cwt   = wts + 393216;   // 256x1152

  PrepArgs pa;
  pa.src[0] = qkvw;         pa.dst[0] = qkvwt;          pa.K[0] = 128; pa.N[0] = 384;
  pa.src[1] = qkvw + 49152; pa.dst[1] = qkvwt + 49152;  pa.K[1] = 128; pa.N[1] = 384;
  pa.src[2] = pw;           pa.dst[2] = pwt;            pa.K[2] = 128; pa.N[2] = 128;
  pa.src[3] = pw + 16384;   pa.dst[3] = pwt + 16384;    pa.K[3] = 128; pa.N[3] = 128;
  pa.src[4] = f1w;          pa.dst[4] = f1wt;           pa.K[4] = 128; pa.N[4] = 512;
  pa.src[5] = f1w + 65536;  pa.dst[5] = f1wt + 65536;   pa.K[5] = 128; pa.N[5] = 512;
  pa.src[6] = f2w;          pa.dst[6] = f2wt;           pa.K[6] = 512; pa.N[6] = 128;
  pa.src[7] = f2w + 65536;  pa.dst[7] = f2wt + 65536;   pa.K[7] = 512; pa.N[7] = 128;
  pa.src[8] = cw;           pa.dst[8] = cwt;            pa.K[8] = 1152; pa.N[8] = 256;
  int cums[10] = {0, 48, 96, 112, 128, 192, 256, 320, 384, 672};
  for (int u = 0; u < 10; ++u) pa.cum[u] = cums[u];
  prep_weights<<<672, 256, 0, stream>>>(pa);

  // layer 0 qkv (standalone, LN1 fused)
  mfma_gemm32<128, 384, 0, 0, 1, 1><<<dim3(196, 6), 256, 0, stream>>>(
      nullptr, x, n1w, n1b, qkvwt, qkvb, nullptr, nullptr, qkv_b, nullptr, 6272);
  natten_mfma<<<784, 128, 0, stream>>>(qkv_b, rpb, att_b);
  // layer 0 MLP + layer 1 LN1+qkv
  mlp_fused3<1><<<392, 512, 0, stream>>>(
      att_b, x, pwt, pb, n2w, n2b, f1wt, f1b, f2wt, f2b, xbuf, nullptr,
      n1w + 128, n1b + 128, qkvwt + 49152, qkvb + 384, qkv_b);
  natten_mfma<<<784, 128, 0, stream>>>(qkv_b, rpb + 676, att_b);
  // layer 1 MLP (+ x copy to d_out tail)
  mlp_fused3<0><<<392, 512, 0, stream>>>(
      att_b, xbuf, pwt + 16384, pb + 128, n2w + 128, n2b + 128,
      f1wt + 65536, f1b + 512, f2wt + 65536, f2b + 128, xbuf, out + 401408,
      nullptr, nullptr, nullptr, nullptr, nullptr);

  conv_gemm32<<<dim3(49, 4, 3), 256, 0, stream>>>(xbuf, cwt, parts);
  ln256_kernel<<<392, 256, 0, stream>>>(parts, parts + 401408, parts + 802816, out, dnw, dnb);
}

// Round 14
// 83.543 us; speedup vs baseline: 1.1372x; 1.1372x over previous
//
#include <hip/hip_runtime.h>
#include <stdint.h>

// ---------------------------------------------------------------------------
// NAT block forward: B=2, H=W=56, C=128, nh=4, hd=32, K=7, depth=2, hidden=512
// Round 14: revert to round-12 structure (best verified: 84.1 us).
// 8 launches: prep, qkv0, nat0, mlp0(+qkv1), nat1, mlp1(+out tail), conv, ln256.
// mlp weights LDS-staged in coalesced 128-row chunks (direct-from-L2 per-lane
// fragments REGRESSED in round 13: uncoalesced 256B-stride lane access).
// ---------------------------------------------------------------------------

typedef __attribute__((ext_vector_type(8))) short bf16x8;
typedef __attribute__((ext_vector_type(4))) float f32x4;

__device__ __forceinline__ float bf2f(uint16_t u) {
  union { uint32_t u; float f; } t;
  t.u = (uint32_t)u << 16;
  return t.f;
}
__device__ __forceinline__ uint16_t f2bf(float f) {
  union { float f; uint32_t u; } t;
  t.f = f;
  return (uint16_t)((t.u + 0x7FFFu + ((t.u >> 16) & 1u)) >> 16);
}

// ---------------------------------------------------------------------------
// One-shot weight prep: 9 transpose+bf16 jobs in one launch (672 blocks).
// ---------------------------------------------------------------------------
struct PrepArgs {
  const float* src[9];
  uint16_t* dst[9];
  int K[9], N[9];
  int cum[10];
};

__global__ __launch_bounds__(256) void prep_weights(PrepArgs a) {
  __shared__ float t[32][33];
  int bt = blockIdx.x;
  int j = 0;
#pragma unroll
  for (int u = 0; u < 9; ++u)
    if (bt >= a.cum[u + 1]) j = u + 1;
  int lt = bt - a.cum[j];
  const float* w = a.src[j];
  uint16_t* wt = a.dst[j];
  int K = a.K[j], N = a.N[j];
  int tn = N >> 5;
  int n0 = (lt % tn) * 32, k0 = (lt / tn) * 32;
  int tx = threadIdx.x & 31, ty = threadIdx.x >> 5;
#pragma unroll
  for (int r2 = 0; r2 < 32; r2 += 8)
    t[ty + r2][tx] = w[(size_t)(k0 + ty + r2) * N + n0 + tx];
  __syncthreads();
#pragma unroll
  for (int r2 = 0; r2 < 32; r2 += 8)
    wt[(size_t)(n0 + ty + r2) * K + k0 + tx] = f2bf(t[tx][ty + r2]);
}

// LayerNorm over C=256 of (p0+p1+p2), fp32 -> fp32. Wave per pixel, float4.
__global__ __launch_bounds__(256) void ln256_kernel(const float* __restrict__ p0,
                                                    const float* __restrict__ p1,
                                                    const float* __restrict__ p2,
                                                    float* __restrict__ out,
                                                    const float* __restrict__ w,
                                                    const float* __restrict__ b) {
  int wave = threadIdx.x >> 6, lane = threadIdx.x & 63;
  int pix = blockIdx.x * 4 + wave;
  size_t base = (size_t)pix * 256 + lane * 4;
  float4 a0 = *(const float4*)(p0 + base);
  float4 a1 = *(const float4*)(p1 + base);
  float4 a2 = *(const float4*)(p2 + base);
  float4 v;
  v.x = a0.x + a1.x + a2.x;
  v.y = a0.y + a1.y + a2.y;
  v.z = a0.z + a1.z + a2.z;
  v.w = a0.w + a1.w + a2.w;
  float s = v.x + v.y + v.z + v.w;
  float s2 = v.x * v.x + v.y * v.y + v.z * v.z + v.w * v.w;
#pragma unroll
  for (int off = 32; off; off >>= 1) {
    s += __shfl_xor(s, off, 64);
    s2 += __shfl_xor(s2, off, 64);
  }
  float mu = s * (1.f / 256.f);
  float var = s2 * (1.f / 256.f) - mu * mu;
  float r = rsqrtf(var + 1e-5f);
  float4 wv = *(const float4*)(w + lane * 4);
  float4 bv = *(const float4*)(b + lane * 4);
  float4 o;
  o.x = (v.x - mu) * r * wv.x + bv.x;
  o.y = (v.y - mu) * r * wv.y + bv.y;
  o.z = (v.z - mu) * r * wv.z + bv.z;
  o.w = (v.w - mu) * r * wv.w + bv.w;
  *(float4*)(out + base) = o;
}

// ---------------------------------------------------------------------------
// MFMA GEMM, 32x64 tile, 4 waves (2x2), wave = 16x32. Used for qkv0 (LNF=1).
// ---------------------------------------------------------------------------
template <int KD, int ND, int ACT, int RES, int OUTB, int LNF>
__global__ __launch_bounds__(256) void mfma_gemm32(
    const uint16_t* __restrict__ A, const float* __restrict__ Af,
    const float* __restrict__ lnw, const float* __restrict__ lnb,
    const uint16_t* __restrict__ Wt, const float* __restrict__ bias,
    const float* __restrict__ res, float* __restrict__ outf,
    uint16_t* __restrict__ outb, float* __restrict__ outf2, int M) {
  __shared__ __align__(16) char smem[26112];  // sA[32][136] | sB[64][136]
  uint16_t(*sA)[136] = (uint16_t(*)[136])smem;
  uint16_t(*sB)[136] = (uint16_t(*)[136])(smem + 8704);
  float(*sC)[68] = (float(*)[68])smem;

  int m0 = blockIdx.x * 32, n0 = blockIdx.y * 64;
  int tid = threadIdx.x, lane = tid & 63, wid = tid >> 6;
  int wr = (wid >> 1) * 16, wc = (wid & 1) * 32;
  int lc = lane & 15, g = lane >> 4;
  int lko = g * 8;

  f32x4 acc0 = {0.f, 0.f, 0.f, 0.f}, acc1 = acc0;

  constexpr int NCH = KD / 128;
#pragma unroll
  for (int c = 0; c < NCH; ++c) {
    if constexpr (LNF) {
      int r = tid >> 3, qt = tid & 7;
      const float4* xr = (const float4*)(Af + (size_t)(m0 + r) * 128 + qt * 16);
      float4 xv[4];
      float s = 0.f, s2 = 0.f;
#pragma unroll
      for (int u = 0; u < 4; ++u) {
        xv[u] = xr[u];
        s += xv[u].x + xv[u].y + xv[u].z + xv[u].w;
        s2 += xv[u].x * xv[u].x + xv[u].y * xv[u].y + xv[u].z * xv[u].z + xv[u].w * xv[u].w;
      }
      s += __shfl_xor(s, 1, 64);
      s += __shfl_xor(s, 2, 64);
      s += __shfl_xor(s, 4, 64);
      s2 += __shfl_xor(s2, 1, 64);
      s2 += __shfl_xor(s2, 2, 64);
      s2 += __shfl_xor(s2, 4, 64);
      float mu = s * (1.f / 128.f);
      float var = s2 * (1.f / 128.f) - mu * mu;
      float rstd = rsqrtf(var + 1e-5f);
      const float* lw = lnw + qt * 16;
      const float* lb = lnb + qt * 16;
      union { uint16_t us[8]; bf16x8 v; } tq[2];
#pragma unroll
      for (int u = 0; u < 4; ++u) {
        tq[u >> 1].us[(u & 1) * 4 + 0] = f2bf((xv[u].x - mu) * rstd * lw[u * 4 + 0] + lb[u * 4 + 0]);
        tq[u >> 1].us[(u & 1) * 4 + 1] = f2bf((xv[u].y - mu) * rstd * lw[u * 4 + 1] + lb[u * 4 + 1]);
        tq[u >> 1].us[(u & 1) * 4 + 2] = f2bf((xv[u].z - mu) * rstd * lw[u * 4 + 2] + lb[u * 4 + 2]);
        tq[u >> 1].us[(u & 1) * 4 + 3] = f2bf((xv[u].w - mu) * rstd * lw[u * 4 + 3] + lb[u * 4 + 3]);
      }
      *(bf16x8*)&sA[r][qt * 16] = tq[0].v;
      *(bf16x8*)&sA[r][qt * 16 + 8] = tq[1].v;
    } else {
#pragma unroll
      for (int it = 0; it < 2; ++it) {
        int chunk = tid + it * 256;
        int row = chunk >> 4, kc = (chunk & 15) * 8;
        *(bf16x8*)&sA[row][kc] =
            *(const bf16x8*)(A + (size_t)(m0 + row) * KD + c * 128 + kc);
      }
    }
#pragma unroll
    for (int it = 0; it < 4; ++it) {
      int chunk = tid + it * 256;
      int row = chunk >> 4, kc = (chunk & 15) * 8;
      *(bf16x8*)&sB[row][kc] =
          *(const bf16x8*)(Wt + (size_t)(n0 + row) * KD + c * 128 + kc);
    }
    __syncthreads();
#pragma unroll
    for (int kk = 0; kk < 128; kk += 32) {
      bf16x8 a0 = *(const bf16x8*)&sA[wr + lc][kk + lko];
      bf16x8 b0 = *(const bf16x8*)&sB[wc + lc][kk + lko];
      bf16x8 b1 = *(const bf16x8*)&sB[wc + 16 + lc][kk + lko];
      acc0 = __builtin_amdgcn_mfma_f32_16x16x32_bf16(a0, b0, acc0, 0, 0, 0);
      acc1 = __builtin_amdgcn_mfma_f32_16x16x32_bf16(a0, b1, acc1, 0, 0, 0);
    }
    __syncthreads();
  }

  {
    float bv0 = bias ? bias[n0 + wc + lc] : 0.f;
    float bv1 = bias ? bias[n0 + wc + lc + 16] : 0.f;
#pragma unroll
    for (int ni = 0; ni < 2; ++ni) {
      float bv = ni ? bv1 : bv0;
      f32x4 av = ni ? acc1 : acc0;
#pragma unroll
      for (int j = 0; j < 4; ++j) {
        float a = av[j] + bv;
        if (ACT) a = 0.5f * a * (1.f + erff(a * 0.70710678118654752f));
        sC[wr + g * 4 + j][wc + ni * 16 + lc] = a;
      }
    }
    __syncthreads();
    int r = tid >> 3, cs = (tid & 7) * 8;
    int grow = m0 + r;
    if (grow < M) {
      const float4* cp = (const float4*)&sC[r][cs];
      float4 c4[2] = {cp[0], cp[1]};
      if (RES) {
        const float4* rp = (const float4*)(res + (size_t)grow * ND + n0 + cs);
#pragma unroll
        for (int u = 0; u < 2; ++u) {
          float4 rv = rp[u];
          c4[u].x += rv.x; c4[u].y += rv.y; c4[u].z += rv.z; c4[u].w += rv.w;
        }
      }
      if (OUTB) {
        union { uint16_t us[8]; bf16x8 v; } t;
#pragma unroll
        for (int u = 0; u < 2; ++u) {
          t.us[u * 4 + 0] = f2bf(c4[u].x);
          t.us[u * 4 + 1] = f2bf(c4[u].y);
          t.us[u * 4 + 2] = f2bf(c4[u].z);
          t.us[u * 4 + 3] = f2bf(c4[u].w);
        }
        *(bf16x8*)(outb + (size_t)grow * ND + n0 + cs) = t.v;
      } else {
        float4* op = (float4*)(outf + (size_t)grow * ND + n0 + cs);
        op[0] = c4[0];
        op[1] = c4[1];
        if (outf2) {
          float4* op2 = (float4*)(outf2 + (size_t)grow * ND + n0 + cs);
          op2[0] = c4[0];
          op2[1] = c4[1];
        }
      }
    }
  }
}

// ---------------------------------------------------------------------------
// Fused MLP tail (+ optional next-layer LN1+qkv): 392 blocks x 512 threads,
// 16 rows/block. All weights staged in coalesced 128-row LDS chunks (sW).
//   y  = x + proj(att) + pb
//   x' = y + fc2(gelu(fc1(LN2(y)))) + f2b          -> xout (+out2)
//   if WQKV: qkv = LN1'(x') @ qkvw' + qkvb'        -> qkvout
// ---------------------------------------------------------------------------
template <int WQKV>
__global__ __launch_bounds__(512) void mlp_fused2(
    const uint16_t* __restrict__ att,   // [6272][128] bf16
    const float* __restrict__ xin,      // [6272][128] f32 (proj residual)
    const uint16_t* __restrict__ pwt,   // [128][128]
    const float* __restrict__ pb,
    const float* __restrict__ n2w, const float* __restrict__ n2b,
    const uint16_t* __restrict__ f1wt,  // [512][128]
    const float* __restrict__ f1b,
    const uint16_t* __restrict__ f2wt,  // [128][512]
    const float* __restrict__ f2b,
    float* __restrict__ xout,
    float* __restrict__ out2,
    const float* __restrict__ n1w, const float* __restrict__ n1b,
    const uint16_t* __restrict__ qwt,   // next-layer qkv [384][128]
    const float* __restrict__ qb,
    uint16_t* __restrict__ qkvout) {
  __shared__ __align__(16) uint16_t sW[128][136];  // 34816 B (weight chunk)
  __shared__ __align__(16) uint16_t sA[16][136];   // 4352 B (activations bf16)
  __shared__ __align__(16) float sY[16][132];      // 8448 B (y, f32)
  __shared__ __align__(16) char sHraw[16640];      // sH bf16[16][520] | sC f32[16][132]
  uint16_t(*sH)[520] = (uint16_t(*)[520])sHraw;
  float(*sC)[132] = (float(*)[132])sHraw;

  const f32x4 fz = {0.f, 0.f, 0.f, 0.f};
  int m0 = blockIdx.x * 16;
  int tid = threadIdx.x;
  int lane = tid & 63, wid = tid >> 6;  // 8 waves
  int lc = lane & 15, g = lane >> 4;
  int rr = tid >> 5, cc = tid & 31;     // 16 rows x 32 threads (4 cols each)

  float4 rx = *(const float4*)(xin + (size_t)(m0 + rr) * 128 + cc * 4);

  if (tid < 256) {
    int r = tid >> 4, q = tid & 15;
    *(bf16x8*)&sA[r][q * 8] = *(const bf16x8*)(att + (size_t)(m0 + r) * 128 + q * 8);
  }
#pragma unroll
  for (int it = 0; it < 4; ++it) {
    int chunk = tid + it * 512;
    int row = chunk >> 4, q = chunk & 15;
    *(bf16x8*)&sW[row][q * 8] = *(const bf16x8*)(pwt + (size_t)row * 128 + q * 8);
  }
  __syncthreads();

  // --- proj ---
  {
    f32x4 acc = fz;
#pragma unroll
    for (int ks = 0; ks < 4; ++ks) {
      bf16x8 a = *(const bf16x8*)&sA[lc][ks * 32 + g * 8];
      bf16x8 b = *(const bf16x8*)&sW[wid * 16 + lc][ks * 32 + g * 8];
      acc = __builtin_amdgcn_mfma_f32_16x16x32_bf16(a, b, acc, 0, 0, 0);
    }
    float bv = pb[wid * 16 + lc];
#pragma unroll
    for (int j = 0; j < 4; ++j) sY[g * 4 + j][wid * 16 + lc] = acc[j] + bv;
  }
  __syncthreads();

  // --- y = proj + x; LN2; norm -> sA ---
  {
    float4 sv = *(const float4*)&sY[rr][cc * 4];
    float4 y;
    y.x = sv.x + rx.x; y.y = sv.y + rx.y; y.z = sv.z + rx.z; y.w = sv.w + rx.w;
    float s = y.x + y.y + y.z + y.w;
    float s2 = y.x * y.x + y.y * y.y + y.z * y.z + y.w * y.w;
#pragma unroll
    for (int off = 1; off < 32; off <<= 1) {
      s += __shfl_xor(s, off, 64);
      s2 += __shfl_xor(s2, off, 64);
    }
    float mu = s * (1.f / 128.f);
    float var = s2 * (1.f / 128.f) - mu * mu;
    float rstd = rsqrtf(var + 1e-5f);
    *(float4*)&sY[rr][cc * 4] = y;
    float4 lw = *(const float4*)(n2w + cc * 4);
    float4 lb = *(const float4*)(n2b + cc * 4);
    ushort4 nv;
    nv.x = f2bf((y.x - mu) * rstd * lw.x + lb.x);
    nv.y = f2bf((y.y - mu) * rstd * lw.y + lb.y);
    nv.z = f2bf((y.z - mu) * rstd * lw.z + lb.z);
    nv.w = f2bf((y.w - mu) * rstd * lw.w + lb.w);
    *(ushort4*)&sA[rr][cc * 4] = nv;
  }
  __syncthreads();

  // --- fc1 + GELU (4 chunks) ---
#pragma unroll 1
  for (int ch = 0; ch < 4; ++ch) {
#pragma unroll
    for (int it = 0; it < 4; ++it) {
      int chunk = tid + it * 512;
      int row = chunk >> 4, q = chunk & 15;
      *(bf16x8*)&sW[row][q * 8] =
          *(const bf16x8*)(f1wt + (size_t)(ch * 128 + row) * 128 + q * 8);
    }
    __syncthreads();
    f32x4 acc = fz;
#pragma unroll
    for (int ks = 0; ks < 4; ++ks) {
      bf16x8 a = *(const bf16x8*)&sA[lc][ks * 32 + g * 8];
      bf16x8 b = *(const bf16x8*)&sW[wid * 16 + lc][ks * 32 + g * 8];
      acc = __builtin_amdgcn_mfma_f32_16x16x32_bf16(a, b, acc, 0, 0, 0);
    }
    int col = ch * 128 + wid * 16 + lc;
    float bv = f1b[col];
#pragma unroll
    for (int j = 0; j < 4; ++j) {
      float h = acc[j] + bv;
      h = 0.5f * h * (1.f + erff(h * 0.70710678118654752f));
      sH[g * 4 + j][col] = f2bf(h);
    }
    __syncthreads();
  }

  // --- fc2 (K=512, 4 chunks) ---
  f32x4 acc2 = fz;
#pragma unroll 1
  for (int ch = 0; ch < 4; ++ch) {
#pragma unroll
    for (int it = 0; it < 4; ++it) {
      int chunk = tid + it * 512;
      int row = chunk >> 4, q = chunk & 15;
      *(bf16x8*)&sW[row][q * 8] =
          *(const bf16x8*)(f2wt + (size_t)row * 512 + ch * 128 + q * 8);
    }
    __syncthreads();
#pragma unroll
    for (int ks = 0; ks < 4; ++ks) {
      bf16x8 a = *(const bf16x8*)&sH[lc][ch * 128 + ks * 32 + g * 8];
      bf16x8 b = *(const bf16x8*)&sW[wid * 16 + lc][ks * 32 + g * 8];
      acc2 = __builtin_amdgcn_mfma_f32_16x16x32_bf16(a, b, acc2, 0, 0, 0);
    }
    __syncthreads();
  }

  // --- +f2b -> sC ---
  {
    int col = wid * 16 + lc;
    float bv = f2b[col];
#pragma unroll
    for (int j = 0; j < 4; ++j) sC[g * 4 + j][col] = acc2[j] + bv;
  }
  __syncthreads();

  // --- x' = y + mlp_out; store; (WQKV) LN1 -> sA ---
  {
    float4 cv = *(const float4*)&sC[rr][cc * 4];
    float4 yv = *(const float4*)&sY[rr][cc * 4];
    float4 o;
    o.x = cv.x + yv.x; o.y = cv.y + yv.y; o.z = cv.z + yv.z; o.w = cv.w + yv.w;
    *(float4*)(xout + (size_t)(m0 + rr) * 128 + cc * 4) = o;
    if (out2) *(float4*)(out2 + (size_t)(m0 + rr) * 128 + cc * 4) = o;
    if constexpr (WQKV) {
      float s = o.x + o.y + o.z + o.w;
      float s2 = o.x * o.x + o.y * o.y + o.z * o.z + o.w * o.w;
#pragma unroll
      for (int off = 1; off < 32; off <<= 1) {
        s += __shfl_xor(s, off, 64);
        s2 += __shfl_xor(s2, off, 64);
      }
      float mu = s * (1.f / 128.f);
      float var = s2 * (1.f / 128.f) - mu * mu;
      float rstd = rsqrtf(var + 1e-5f);
      float4 lw = *(const float4*)(n1w + cc * 4);
      float4 lb = *(const float4*)(n1b + cc * 4);
      ushort4 nv;
      nv.x = f2bf((o.x - mu) * rstd * lw.x + lb.x);
      nv.y = f2bf((o.y - mu) * rstd * lw.y + lb.y);
      nv.z = f2bf((o.z - mu) * rstd * lw.z + lb.z);
      nv.w = f2bf((o.w - mu) * rstd * lw.w + lb.w);
      *(ushort4*)&sA[rr][cc * 4] = nv;
    }
  }

  if constexpr (WQKV) {
    // --- qkv: 3 chunks of 128 output cols; outputs staged in sH (bf16) ---
#pragma unroll 1
    for (int ch = 0; ch < 3; ++ch) {
#pragma unroll
      for (int it = 0; it < 4; ++it) {
        int chunk = tid + it * 512;
        int row = chunk >> 4, q = chunk & 15;
        *(bf16x8*)&sW[row][q * 8] =
            *(const bf16x8*)(qwt + (size_t)(ch * 128 + row) * 128 + q * 8);
      }
      __syncthreads();  // also fences sC reads (ch==0) and prior sW use
      f32x4 acc = fz;
#pragma unroll
      for (int ks = 0; ks < 4; ++ks) {
        bf16x8 a = *(const bf16x8*)&sA[lc][ks * 32 + g * 8];
        bf16x8 b = *(const bf16x8*)&sW[wid * 16 + lc][ks * 32 + g * 8];
        acc = __builtin_amdgcn_mfma_f32_16x16x32_bf16(a, b, acc, 0, 0, 0);
      }
      int col = ch * 128 + wid * 16 + lc;
      float bv = qb[col];
#pragma unroll
      for (int j = 0; j < 4; ++j) sH[g * 4 + j][col] = f2bf(acc[j] + bv);
      __syncthreads();
    }
    // coalesced store: 16 rows x 384 bf16
    for (int idx = tid; idx < 1536; idx += 512) {
      int row = idx / 96, colc = (idx % 96) * 4;
      *(ushort4*)(qkvout + (size_t)(m0 + row) * 384 + colc) =
          *(const ushort4*)&sH[row][colc];
    }
  }
}

// ---------------------------------------------------------------------------
// Neighborhood attention via MFMA. Block = (b, head, 8x4 q-tile), 784 blocks
// of 128 threads (2 waves x 16 q). Halo 10x14 = 140 keys, padded to 160.
// ---------------------------------------------------------------------------
#define KSWZ(row, colbytes) (((row) * 64 + (colbytes)) ^ (((row) & 7) << 4))

__global__ __launch_bounds__(128) void natten_mfma(const uint16_t* __restrict__ qkv,
                                                   const float* __restrict__ rpb,
                                                   uint16_t* __restrict__ out) {
  __shared__ uint16_t s_k[144 * 32];
  __shared__ uint16_t s_vt[32][168];
  __shared__ uint16_t s_p[32][168];
  __shared__ float s_rpb[169];

  int tid = threadIdx.x;
  int blk = blockIdx.x;
  int bh = blk & 7, tile = blk >> 3;
  int b = bh >> 2, head = bh & 3;
  int ti = tile / 7, tj = tile % 7;
  int i0 = ti * 4, j0 = tj * 8;
  int rbase = min(max(i0 - 3, 0), 46);
  int cbase = min(max(j0 - 3, 0), 42);

  const bf16x8 bz = {0, 0, 0, 0, 0, 0, 0, 0};
  const f32x4 fz = {0.f, 0.f, 0.f, 0.f};

  if (tid < 16)
    *(bf16x8*)((char*)s_k + KSWZ(140 + (tid >> 2), (tid & 3) * 16)) = bz;
  for (int idx = tid; idx < 640; idx += 128) s_vt[idx & 31][140 + (idx >> 5)] = 0;
  for (int idx = tid; idx < 512; idx += 128) s_p[idx & 31][144 + (idx >> 5)] = 0;
  for (int idx = tid; idx < 560; idx += 128) {
    int pos = idx >> 2, ch = (idx & 3) * 8;
    int r = rbase + pos / 14, c = cbase + pos % 14;
    const uint16_t* base = qkv + ((size_t)(b * 3136 + r * 56 + c)) * 384 + head * 32 + ch;
    bf16x8 kv = *(const bf16x8*)(base + 128);
    bf16x8 vv = *(const bf16x8*)(base + 256);
    *(bf16x8*)((char*)s_k + KSWZ(pos, ch * 2)) = kv;
#pragma unroll
    for (int e = 0; e < 8; ++e) s_vt[ch + e][pos] = (uint16_t)vv[e];
  }
  for (int idx = tid; idx < 169; idx += 128) s_rpb[idx] = rpb[head * 169 + idx];
  __syncthreads();

  int lane = tid & 63, wq = tid >> 6;
  int lc = lane & 15, g = lane >> 4;
  int q0 = wq * 16;

  int pA = q0 + lc;
  int piA = i0 + (pA >> 3), pjA = j0 + (pA & 7);
  bf16x8 qfrag =
      *(const bf16x8*)(qkv + ((size_t)(b * 3136 + piA * 56 + pjA)) * 384 + head * 32 + g * 8);

  f32x4 S[9];
#pragma unroll
  for (int t = 0; t < 9; ++t) {
    bf16x8 kfrag = *(const bf16x8*)((char*)s_k + KSWZ(t * 16 + lc, g * 16));
    S[t] = __builtin_amdgcn_mfma_f32_16x16x32_bf16(qfrag, kfrag, fz, 0, 0, 0);
  }

  int qi = wq * 2 + (g >> 1);
  int i = i0 + qi;
  int a = min(max(i - 3, 0), 49) - rbase;
  int brc = 6 - (i0 - rbase) - qi;
  int bj[4], bcc[4];
#pragma unroll
  for (int jj = 0; jj < 4; ++jj) {
    int qj = 4 * (g & 1) + jj;
    int j = j0 + qj;
    bj[jj] = min(max(j - 3, 0), 49) - cbase;
    bcc[jj] = 6 - (j0 - cbase) - qj;
  }

  float mx[4] = {-1e30f, -1e30f, -1e30f, -1e30f};
  int kr = (lc >= 14) ? 1 : 0;
  int kc = lc - 14 * kr;
#pragma unroll
  for (int t = 0; t < 9; ++t) {
    bool vr = (kr >= a) && (kr <= a + 6);
    int brrow = (kr + brc) * 13;
#pragma unroll
    for (int jj = 0; jj < 4; ++jj) {
      float sv = S[t][jj] * 0.17677669529663687f;
      bool v = vr && (kc >= bj[jj]) && (kc <= bj[jj] + 6);
      int bidx = v ? (brrow + kc + bcc[jj]) : 0;
      float val = v ? (sv + s_rpb[bidx]) : -1e30f;
      S[t][jj] = val;
      mx[jj] = fmaxf(mx[jj], val);
    }
    kr += 1;
    kc += 2;
    if (kc >= 14) { kc -= 14; kr += 1; }
  }
#pragma unroll
  for (int jj = 0; jj < 4; ++jj) {
#pragma unroll
    for (int off = 1; off < 16; off <<= 1) mx[jj] = fmaxf(mx[jj], __shfl_xor(mx[jj], off, 64));
  }

  float sm[4] = {0.f, 0.f, 0.f, 0.f};
#pragma unroll
  for (int t = 0; t < 9; ++t) {
#pragma unroll
    for (int jj = 0; jj < 4; ++jj) {
      float e = __expf(S[t][jj] - mx[jj]);
      sm[jj] += e;
      s_p[q0 + g * 4 + jj][t * 16 + lc] = f2bf(e);
    }
  }
#pragma unroll
  for (int jj = 0; jj < 4; ++jj) {
#pragma unroll
    for (int off = 1; off < 16; off <<= 1) sm[jj] += __shfl_xor(sm[jj], off, 64);
    sm[jj] = 1.f / sm[jj];
  }

  __syncthreads();

  f32x4 O[2] = {fz, fz};
#pragma unroll
  for (int ks = 0; ks < 5; ++ks) {
    bf16x8 pa = *(const bf16x8*)&s_p[q0 + lc][ks * 32 + g * 8];
#pragma unroll
    for (int dt = 0; dt < 2; ++dt) {
      bf16x8 vb = *(const bf16x8*)&s_vt[dt * 16 + lc][ks * 32 + g * 8];
      O[dt] = __builtin_amdgcn_mfma_f32_16x16x32_bf16(pa, vb, O[dt], 0, 0, 0);
    }
  }

#pragma unroll
  for (int jj = 0; jj < 4; ++jj) {
    int q = q0 + g * 4 + jj;
    int pi = i0 + (q >> 3), pj = j0 + (q & 7);
    size_t ob = ((size_t)(b * 3136 + pi * 56 + pj)) * 128 + head * 32;
    out[ob + lc] = f2bf(O[0][jj] * sm[jj]);
    out[ob + 16 + lc] = f2bf(O[1][jj] * sm[jj]);
  }
}

// ---------------------------------------------------------------------------
// Conv GEMM, split-K by kh (blockIdx.z). Grid (49, 4, 3). 32x64 tile.
// ---------------------------------------------------------------------------
__global__ __launch_bounds__(256) void conv_gemm32(const float* __restrict__ x,
                                                   const uint16_t* __restrict__ Wt,
                                                   float* __restrict__ parts) {
  __shared__ __align__(16) char smem[26112];
  uint16_t(*sA)[136] = (uint16_t(*)[136])smem;
  uint16_t(*sB)[136] = (uint16_t(*)[136])(smem + 8704);
  float(*sC)[68] = (float(*)[68])smem;

  int m0 = blockIdx.x * 32, n0 = blockIdx.y * 64, kh = blockIdx.z;
  float* part = parts + (size_t)kh * 1568 * 256;
  int tid = threadIdx.x, lane = tid & 63, wid = tid >> 6;
  int wr = (wid >> 1) * 16, wc = (wid & 1) * 32;
  int lc = lane & 15, g = lane >> 4;
  int lko = g * 8;

  f32x4 acc0 = {0.f, 0.f, 0.f, 0.f}, acc1 = acc0;

  int r = tid >> 3, qt = tid & 7;
  int opix = m0 + r;
  int ow = opix % 28, oh = (opix / 28) % 28, bb = opix / 784;
  int ih = 2 * oh - 1 + kh;
  bool rowok = (ih >= 0) && (ih < 56);

#pragma unroll
  for (int kwc = 0; kwc < 3; ++kwc) {
    int iw = 2 * ow - 1 + kwc;
    float4 xv[4] = {{0.f, 0.f, 0.f, 0.f}, {0.f, 0.f, 0.f, 0.f},
                    {0.f, 0.f, 0.f, 0.f}, {0.f, 0.f, 0.f, 0.f}};
    if (rowok && iw >= 0 && iw < 56) {
      const float4* p =
          (const float4*)(x + (size_t)((bb * 56 + ih) * 56 + iw) * 128 + qt * 16);
#pragma unroll
      for (int u = 0; u < 4; ++u) xv[u] = p[u];
    }
    union { uint16_t us[8]; bf16x8 v; } tq[2];
#pragma unroll
    for (int u = 0; u < 4; ++u) {
      tq[u >> 1].us[(u & 1) * 4 + 0] = f2bf(xv[u].x);
      tq[u >> 1].us[(u & 1) * 4 + 1] = f2bf(xv[u].y);
      tq[u >> 1].us[(u & 1) * 4 + 2] = f2bf(xv[u].z);
      tq[u >> 1].us[(u & 1) * 4 + 3] = f2bf(xv[u].w);
    }
    *(bf16x8*)&sA[r][qt * 16] = tq[0].v;
    *(bf16x8*)&sA[r][qt * 16 + 8] = tq[1].v;
#pragma unroll
    for (int it = 0; it < 4; ++it) {
      int chunk = tid + it * 256;
      int row = chunk >> 4, kc = (chunk & 15) * 8;
      *(bf16x8*)&sB[row][kc] =
          *(const bf16x8*)(Wt + (size_t)(n0 + row) * 1152 + kh * 384 + kwc * 128 + kc);
    }
    __syncthreads();
#pragma unroll
    for (int kk = 0; kk < 128; kk += 32) {
      bf16x8 a0 = *(const bf16x8*)&sA[wr + lc][kk + lko];
      bf16x8 b0 = *(const bf16x8*)&sB[wc + lc][kk + lko];
      bf16x8 b1 = *(const bf16x8*)&sB[wc + 16 + lc][kk + lko];
      acc0 = __builtin_amdgcn_mfma_f32_16x16x32_bf16(a0, b0, acc0, 0, 0, 0);
      acc1 = __builtin_amdgcn_mfma_f32_16x16x32_bf16(a0, b1, acc1, 0, 0, 0);
    }
    __syncthreads();
  }

#pragma unroll
  for (int ni = 0; ni < 2; ++ni) {
    f32x4 av = ni ? acc1 : acc0;
#pragma unroll
    for (int j = 0; j < 4; ++j) sC[wr + g * 4 + j][wc + ni * 16 + lc] = av[j];
  }
  __syncthreads();
  int rr = tid >> 3, cs = (tid & 7) * 8;
  int grow = m0 + rr;
  if (grow < 1568) {
    const float4* cp = (const float4*)&sC[rr][cs];
    float4* op = (float4*)(part + (size_t)grow * 256 + n0 + cs);
    op[0] = cp[0];
    op[1] = cp[1];
  }
}

extern "C" void kernel_launch(void* const* d_in, const int* in_sizes, int n_in,
                              void* d_out, int out_size, void* d_ws, size_t ws_size,
                              hipStream_t stream) {
  const float* x    = (const float*)d_in[0];
  const float* n1w  = (const float*)d_in[1];
  const float* n1b  = (const float*)d_in[2];
  const float* qkvw = (const float*)d_in[3];
  const float* qkvb = (const float*)d_in[4];
  const float* rpb  = (const float*)d_in[5];
  const float* pw   = (const float*)d_in[6];
  const float* pb   = (const float*)d_in[7];
  const float* n2w  = (const float*)d_in[8];
  const float* n2b  = (const float*)d_in[9];
  const float* f1w  = (const float*)d_in[10];
  const float* f1b  = (const float*)d_in[11];
  const float* f2w  = (const float*)d_in[12];
  const float* f2b  = (const float*)d_in[13];
  const float* cw   = (const float*)d_in[14];
  const float* dnw  = (const float*)d_in[15];
  const float* dnb  = (const float*)d_in[16];
  float* out = (float*)d_out;

  char* wsb = (char*)d_ws;
  float*    xbuf    = (float*)(wsb + 0);           // 3211264 B
  uint16_t* qkv_b   = (uint16_t*)(wsb + 3211264);  // 4816896 B
  uint16_t* att_b   = (uint16_t*)(wsb + 8028160);  // 1605632 B
  float*    parts   = (float*)(wsb + 16056320);    // 3 x 1605632 B
  uint16_t* wts     = (uint16_t*)(wsb + 20873216); // 1376256 B
  uint16_t* qkvwt = wts;            // 2 x 384x128
  uint16_t* pwt   = wts + 98304;    // 2 x 128x128
  uint16_t* f1wt  = wts + 131072;   // 2 x 512x128
  uint16_t* f2wt  = wts + 262144;   // 2 x 128x512
  uint16_t* cwt   = wts + 393216;   // 256x1152

  PrepArgs pa;
  pa.src[0] = qkvw;         pa.dst[0] = qkvwt;          pa.K[0] = 128; pa.N[0] = 384;
  pa.src[1] = qkvw + 49152; pa.dst[1] = qkvwt + 49152;  pa.K[1] = 128; pa.N[1] = 384;
  pa.src[2] = pw;           pa.dst[2] = pwt;            pa.K[2] = 128; pa.N[2] = 128;
  pa.src[3] = pw + 16384;   pa.dst[3] = pwt + 16384;    pa.K[3] = 128; pa.N[3] = 128;
  pa.src[4] = f1w;          pa.dst[4] = f1wt;           pa.K[4] = 128; pa.N[4] = 512;
  pa.src[5] = f1w + 65536;  pa.dst[5] = f1wt + 65536;   pa.K[5] = 128; pa.N[5] = 512;
  pa.src[6] = f2w;          pa.dst[6] = f2wt;           pa.K[6] = 512; pa.N[6] = 128;
  pa.src[7] = f2w + 65536;  pa.dst[7] = f2wt + 65536;   pa.K[7] = 512; pa.N[7] = 128;
  pa.src[8] = cw;           pa.dst[8] = cwt;            pa.K[8] = 1152; pa.N[8] = 256;
  int cums[10] = {0, 48, 96, 112, 128, 192, 256, 320, 384, 672};
  for (int u = 0; u < 10; ++u) pa.cum[u] = cums[u];
  prep_weights<<<672, 256, 0, stream>>>(pa);

  // layer 0 qkv (standalone, LN1 fused)
  mfma_gemm32<128, 384, 0, 0, 1, 1><<<dim3(196, 6), 256, 0, stream>>>(
      nullptr, x, n1w, n1b, qkvwt, qkvb, nullptr, nullptr, qkv_b, nullptr, 6272);
  natten_mfma<<<784, 128, 0, stream>>>(qkv_b, rpb, att_b);
  // layer 0 MLP + layer 1 LN1+qkv
  mlp_fused2<1><<<392, 512, 0, stream>>>(
      att_b, x, pwt, pb, n2w, n2b, f1wt, f1b, f2wt, f2b, xbuf, nullptr,
      n1w + 128, n1b + 128, qkvwt + 49152, qkvb + 384, qkv_b);
  natten_mfma<<<784, 128, 0, stream>>>(qkv_b, rpb + 676, att_b);
  // layer 1 MLP (+ x copy to d_out tail)
  mlp_fused2<0><<<392, 512, 0, stream>>>(
      att_b, xbuf, pwt + 16384, pb + 128, n2w + 128, n2b + 128,
      f1wt + 65536, f1b + 512, f2wt + 65536, f2b + 128, xbuf, out + 401408,
      nullptr, nullptr, nullptr, nullptr, nullptr);

  conv_gemm32<<<dim3(49, 4, 3), 256, 0, stream>>>(xbuf, cwt, parts);
  ln256_kernel<<<392, 256, 0, stream>>>(parts, parts + 401408, parts + 802816, out, dnw, dnb);
}